// Round 3
// baseline (7002.212 us; speedup 1.0000x reference)
//
#include <hip/hip_runtime.h>
#include <hip/hip_bf16.h>

#define D 128
#define OSTR 136   // LDS row stride (shorts) for epilogue transpose

typedef float f32x4  __attribute__((ext_vector_type(4)));
typedef __attribute__((ext_vector_type(8))) __bf16 bh8;

union UV { uint4 u; bh8 h; };

__device__ inline float bf2f(unsigned short u) {
    union { unsigned int i; float f; } x; x.i = ((unsigned int)u) << 16; return x.f;
}
__device__ inline unsigned short f2bf(float f) {
    union { float f; unsigned int i; } x; x.f = f;
    return (unsigned short)((x.i + 0x7fffu + ((x.i >> 16) & 1u)) >> 16);
}
__device__ inline void acc2(unsigned int u, float& a, float& b) {
    union { unsigned int i; float f; } lo, hi;
    lo.i = u << 16; hi.i = u & 0xffff0000u;
    a += lo.f; b += hi.f;
}
__device__ inline unsigned int addb2(unsigned int ua, unsigned int ub) {
    union { unsigned int i; float f; } la, ha, lb, hb;
    la.i = ua << 16; ha.i = ua & 0xffff0000u;
    lb.i = ub << 16; hb.i = ub & 0xffff0000u;
    return ((unsigned int)f2bf(ha.f + hb.f) << 16) | f2bf(la.f + lb.f);
}

// ---------------- CSR build ----------------
__global__ void k_hist(const int* __restrict__ edges, int E, int* __restrict__ deg) {
    int e = blockIdx.x * blockDim.x + threadIdx.x;
    if (e < E) {
        atomicAdd(&deg[edges[2 * e]], 1);
        atomicAdd(&deg[edges[2 * e + 1]], 1);
    }
}

__global__ void k_scan1(const int* __restrict__ deg, int n,
                        int* __restrict__ incl, int* __restrict__ bsum) {
    __shared__ int lds[1024];
    int t = threadIdx.x;
    int i = blockIdx.x * 1024 + t;
    int v = (i < n) ? deg[i] : 0;
    int cur = v;
    lds[t] = cur;
    __syncthreads();
    for (int off = 1; off < 1024; off <<= 1) {
        int add = (t >= off) ? lds[t - off] : 0;
        __syncthreads();
        cur += add;
        lds[t] = cur;
        __syncthreads();
    }
    if (i < n) incl[i] = cur;
    if (t == 1023) bsum[blockIdx.x] = cur;
}

__global__ void k_scan2(int* __restrict__ bsum, int nb) {
    __shared__ int lds[128];
    int t = threadIdx.x;
    int v = (t < nb) ? bsum[t] : 0;
    int cur = v;
    lds[t] = cur;
    __syncthreads();
    for (int off = 1; off < 128; off <<= 1) {
        int add = (t >= off) ? lds[t - off] : 0;
        __syncthreads();
        cur += add;
        lds[t] = cur;
        __syncthreads();
    }
    if (t < nb) bsum[t] = cur - v;  // exclusive
}

__global__ void k_scan3(const int* __restrict__ incl, const int* __restrict__ deg,
                        const int* __restrict__ bsum, int n, int twoE,
                        int* __restrict__ rowstart, int* __restrict__ cursor) {
    int i = blockIdx.x * blockDim.x + threadIdx.x;
    if (i < n) {
        int r = incl[i] - deg[i] + bsum[i >> 10];
        rowstart[i] = r;
        cursor[i] = r;
    }
    if (i == 0) rowstart[n] = twoE;
}

__global__ void k_fill(const int* __restrict__ edges, int E,
                       int* __restrict__ cursor, int* __restrict__ adj,
                       int* __restrict__ own) {
    int e = blockIdx.x * blockDim.x + threadIdx.x;
    if (e < E) {
        int a = edges[2 * e], b = edges[2 * e + 1];
        int pa = atomicAdd(&cursor[a], 1);
        adj[pa] = b; own[pa] = a;
        int pb = atomicAdd(&cursor[b], 1);
        adj[pb] = a; own[pb] = b;
    }
}

// ---------------- weight prep: bf16, K-chunked layout ----------------
// wb[l][chunk=kk>>5][o][kk&31], kk = m*128+k (m=0: W0, m=1: W1)
__global__ void k_wprep(const float* __restrict__ W0_1, const float* __restrict__ W1_1,
                        const float* __restrict__ W0_h, const float* __restrict__ W1_h,
                        unsigned short* __restrict__ wb) {
    int idx = blockIdx.x * 256 + threadIdx.x;
    if (idx >= 13 * 2 * 128 * 128) return;
    int k = idx & 127;
    int o = (idx >> 7) & 127;
    int m = (idx >> 14) & 1;
    int l = idx >> 15;
    const float* src = (l == 0) ? (m ? W1_1 : W0_1)
                                : ((m ? W1_h : W0_h) + (size_t)(l - 1) * 16384);
    float v = src[o * 128 + k];
    int kk = m * 128 + k;
    wb[(size_t)l * 32768 + (kk >> 5) * 4096 + o * 32 + (kk & 31)] = f2bf(v);
}

// ---------------- fp32 -> bf16 convert ----------------
__global__ void k_cvt(const float* __restrict__ in, unsigned short* __restrict__ out, int n4) {
    int i = blockIdx.x * blockDim.x + threadIdx.x;
    if (i >= n4) return;
    f32x4 v = *(const f32x4*)&in[(size_t)i * 4];
    unsigned short u[4];
    #pragma unroll
    for (int j = 0; j < 4; ++j) u[j] = f2bf(v[j]);
    *(uint2*)&out[(size_t)i * 4] = *(uint2*)u;
}

// ---------------- standalone neighbor aggregation (final layer only) ----------------
__global__ __launch_bounds__(256) void k_agg(
    const unsigned short* __restrict__ x, const int* __restrict__ rowstart,
    const int* __restrict__ adj, unsigned short* __restrict__ s, int n) {
    int node = blockIdx.x * 4 + (threadIdx.x >> 6);
    int lane = threadIdx.x & 63;
    if (node >= n) return;
    int r0 = rowstart[node], r1 = rowstart[node + 1];
    float a[8], b[8];
    #pragma unroll
    for (int k = 0; k < 8; ++k) { a[k] = 0.f; b[k] = 0.f; }
    for (int p = r0; p < r1; p += 8) {
        int q = p + (lane & 7);
        int idx = (q < r1) ? adj[q] : 0;
        unsigned int u[8];
        #pragma unroll
        for (int k = 0; k < 8; ++k) {
            int j = __shfl(idx, k);
            u[k] = *(const unsigned int*)&x[(size_t)j * D + lane * 2];
        }
        #pragma unroll
        for (int k = 0; k < 8; ++k)
            if (p + k < r1) acc2(u[k], a[k], b[k]);
    }
    float f0 = ((a[0] + a[1]) + (a[2] + a[3])) + ((a[4] + a[5]) + (a[6] + a[7]));
    float f1 = ((b[0] + b[1]) + (b[2] + b[3])) + ((b[4] + b[5]) + (b[6] + b[7]));
    unsigned int out = ((unsigned int)f2bf(f1) << 16) | f2bf(f0);
    *(unsigned int*)&s[(size_t)node * D + lane * 2] = out;
}

// ---------------- fused layer: edge-parallel agg (LDS fp32 atomics) + MFMA GEMM ----------------
// Block = 128 nodes, 4 waves, 64KB LDS fp32 s-tile [128][128].
// Phase 0: zero-init tile. Phase 1: waves split the block's contiguous CSR edge
// range; 16-deep double-buffered stream of independent row loads; each edge adds
// its row into owner's tile row via ds_add_f32 (owner from own[]). Phase 2:
// in-place fp32->bf16 with XOR swizzle (conflict-free ds_read_b128 later).
// Phase 3: GEMM (A kc<4 from global x, kc>=4 from swizzled tile, B from global).
// Epilogue: bias + deg*b1 + relu -> LDS transpose -> coalesced stores.
__global__ __launch_bounds__(256, 2) void k_fused(
    const unsigned short* __restrict__ x,    // [n][128] bf16
    const unsigned short* __restrict__ wb,   // layer weights, chunked [8][128][32] bf16
    const float* __restrict__ bias0, const float* __restrict__ bias1,
    const int* __restrict__ rowstart, const int* __restrict__ adj,
    const int* __restrict__ own,
    const int* __restrict__ deg,
    unsigned short* __restrict__ out,        // [n][128] bf16
    float* __restrict__ out32,               // optional fp32 copy (aux), may be null
    const unsigned short* __restrict__ resid,// optional residual input (bf16)
    unsigned short* __restrict__ zout,       // optional: zout = out + resid
    int n, int do_relu) {
    __shared__ __align__(16) unsigned char LDSB[65536];
    float* Sf = (float*)LDSB;
    int t = threadIdx.x;
    int lane = t & 63;
    int wave = t >> 6;
    int node0 = blockIdx.x * 128;

    // ---- phase 0: zero the fp32 tile ----
    {
        uint4 z = {0u, 0u, 0u, 0u};
        #pragma unroll
        for (int j = 0; j < 16; ++j)
            *(uint4*)&LDSB[t * 256 + j * 16] = z;
    }
    __syncthreads();

    // ---- phase 1: edge-parallel gather with LDS fp32 atomics ----
    {
        int nhi = node0 + 128; if (nhi > n) nhi = n;
        int e0b = rowstart[node0];
        int e1b = rowstart[nhi];
        int tot = e1b - e0b;
        int chunk = (tot + 3) >> 2;
        int e0 = e0b + wave * chunk;
        int e1 = e0 + chunk;
        if (e1 > e1b) e1 = e1b;
        if (e0 > e1b) e0 = e1b;

        for (int base = e0; base < e1; base += 64) {
            int q = base + lane;
            int aidx = 0, aown = 0;
            if (q < e1) { aidx = adj[q]; aown = own[q] - node0; }
            int m = e1 - base; if (m > 64) m = 64;

            unsigned int u[16], v[16];
            auto LD = [&](unsigned int* buf, int off) {
                #pragma unroll
                for (int k = 0; k < 16; ++k) {
                    int j = __builtin_amdgcn_readlane(aidx, off + k);
                    buf[k] = *(const unsigned int*)&x[(size_t)j * D + lane * 2];
                }
            };
            auto ACC = [&](const unsigned int* buf, int off) {
                #pragma unroll
                for (int k = 0; k < 16; ++k) {
                    if (off + k < m) {
                        int o = __builtin_amdgcn_readlane(aown, off + k);
                        union { unsigned int i; float f; } lo, hi;
                        lo.i = buf[k] << 16; hi.i = buf[k] & 0xffff0000u;
                        atomicAdd(&Sf[o * 128 + 2 * lane], lo.f);
                        atomicAdd(&Sf[o * 128 + 2 * lane + 1], hi.f);
                    }
                }
            };
            LD(u, 0);
            if (m > 16) LD(v, 16);
            ACC(u, 0);
            if (m > 16) {
                if (m > 32) LD(u, 32);
                ACC(v, 16);
                if (m > 32) {
                    if (m > 48) LD(v, 48);
                    ACC(u, 32);
                    if (m > 48) ACC(v, 48);
                }
            }
        }
    }
    __syncthreads();

    // ---- phase 2: in-place fp32 -> bf16 with XOR swizzle ----
    // bf16 row r lives at byte r*512 + ((colbyte) ^ ((r&7)<<4)), colbyte in [0,256)
    {
        #pragma unroll 4
        for (int rr = 0; rr < 32; ++rr) {
            int r = wave * 32 + rr;
            float f0 = Sf[r * 128 + 2 * lane];
            float f1 = Sf[r * 128 + 2 * lane + 1];
            unsigned int pk = ((unsigned int)f2bf(f1) << 16) | f2bf(f0);
            *(unsigned int*)&LDSB[r * 512 + ((4 * lane) ^ ((r & 7) << 4))] = pk;
        }
    }
    __syncthreads();

    // ---- phase 3: GEMM, no barriers in loop ----
    int wm = (wave & 1) * 64;
    int wn = (wave >> 1) * 64;
    int mlane = lane & 15;
    int quad = lane >> 4;

    f32x4 acc[4][4];
    #pragma unroll
    for (int i = 0; i < 4; ++i)
        #pragma unroll
        for (int j = 0; j < 4; ++j) acc[i][j] = (f32x4){0.f, 0.f, 0.f, 0.f};

    #pragma unroll
    for (int kc = 0; kc < 8; ++kc) {
        bh8 af[4], bf_[4];
        #pragma unroll
        for (int i = 0; i < 4; ++i) {
            int r = wm + i * 16 + mlane;
            if (kc < 4) {
                int g = node0 + r;
                UV v; v.u = (uint4){0u, 0u, 0u, 0u};
                if (g < n) v.u = *(const uint4*)&x[(size_t)g * D + kc * 32 + quad * 8];
                af[i] = v.h;
            } else {
                int c0 = ((kc - 4) * 64 + quad * 16) ^ ((r & 7) << 4);
                af[i] = *(const bh8*)&LDSB[r * 512 + c0];
            }
        }
        #pragma unroll
        for (int j = 0; j < 4; ++j)
            bf_[j] = *(const bh8*)&wb[(size_t)kc * 4096 + (wn + j * 16 + mlane) * 32 + quad * 8];
        #pragma unroll
        for (int i = 0; i < 4; ++i)
            #pragma unroll
            for (int j = 0; j < 4; ++j)
                acc[i][j] = __builtin_amdgcn_mfma_f32_16x16x32_bf16(af[i], bf_[j], acc[i][j], 0, 0, 0);
    }

    // ---- epilogue: bias + deg*b1 + relu -> LDS transpose -> coalesced stores ----
    __syncthreads();   // tile fully consumed; reuse LDS as O-tile [128][OSTR] bf16
    unsigned short* Ol = (unsigned short*)LDSB;
    #pragma unroll
    for (int i = 0; i < 4; ++i) {
        int mrow = wm + i * 16 + quad * 4;
        #pragma unroll
        for (int j = 0; j < 4; ++j) {
            int nn = wn + j * 16 + mlane;
            float b0v = bias0[nn], b1v = bias1[nn];
            #pragma unroll
            for (int r = 0; r < 4; ++r) {
                int g = node0 + mrow + r;
                float dg = (g < n) ? (float)deg[g] : 0.f;
                float val = acc[i][j][r] + b0v + dg * b1v;
                if (do_relu) val = fmaxf(val, 0.f);
                Ol[(mrow + r) * OSTR + nn] = f2bf(val);
            }
        }
    }
    __syncthreads();
    // bf16 store: 8 passes, 16 lanes x 16B = one full 256B node row per 16 threads
    #pragma unroll
    for (int pass = 0; pass < 8; ++pass) {
        int row = pass * 16 + (t >> 4);
        int seg = (t & 15) * 8;
        int g = node0 + row;
        if (g < n) {
            uint4 v = *(const uint4*)&Ol[row * OSTR + seg];
            *(uint4*)&out[(size_t)g * D + seg] = v;
            if (zout) {
                uint4 rr = *(const uint4*)&resid[(size_t)g * D + seg];
                uint4 zz;
                zz.x = addb2(v.x, rr.x);
                zz.y = addb2(v.y, rr.y);
                zz.z = addb2(v.z, rr.z);
                zz.w = addb2(v.w, rr.w);
                *(uint4*)&zout[(size_t)g * D + seg] = zz;
            }
        }
    }
    if (out32) {
        #pragma unroll
        for (int pass = 0; pass < 16; ++pass) {
            int row = pass * 8 + (t >> 5);
            int seg = (t & 31) * 4;
            int g = node0 + row;
            if (g < n) {
                f32x4 v;
                #pragma unroll
                for (int j = 0; j < 4; ++j) v[j] = bf2f(Ol[row * OSTR + seg + j]);
                *(f32x4*)&out32[(size_t)g * D + seg] = v;
            }
        }
    }
}

// ---------------- last layer (D_out = 3, fp32 out, no relu) ----------------
__global__ void k_last(const unsigned short* __restrict__ z, const unsigned short* __restrict__ sz,
                       const float* __restrict__ W0, const float* __restrict__ b0,
                       const float* __restrict__ W1, const float* __restrict__ b1,
                       const int* __restrict__ deg, float* __restrict__ vert, int n) {
    int t = threadIdx.x;
    int lane = t & 63;
    int node = blockIdx.x * 4 + (t >> 6);
    if (node >= n) return;
    float z0 = bf2f(z[(size_t)node * D + lane]), z1 = bf2f(z[(size_t)node * D + 64 + lane]);
    float s0 = bf2f(sz[(size_t)node * D + lane]), s1 = bf2f(sz[(size_t)node * D + 64 + lane]);
    float dg = (float)deg[node];
    #pragma unroll
    for (int o = 0; o < 3; ++o) {
        float p = z0 * W0[o * D + lane] + z1 * W0[o * D + 64 + lane]
                + s0 * W1[o * D + lane] + s1 * W1[o * D + 64 + lane];
        for (int off = 32; off > 0; off >>= 1) p += __shfl_down(p, off);
        if (lane == 0) vert[(size_t)node * 3 + o] = p + b0[o] + dg * b1[o];
    }
}

extern "C" void kernel_launch(void* const* d_in, const int* in_sizes, int n_in,
                              void* d_out, int out_size, void* d_ws, size_t ws_size,
                              hipStream_t stream) {
    const float* features = (const float*)d_in[0];
    const int*   edges    = (const int*)d_in[1];
    const float* W0_1 = (const float*)d_in[2];
    const float* b0_1 = (const float*)d_in[3];
    const float* W1_1 = (const float*)d_in[4];
    const float* b1_1 = (const float*)d_in[5];
    const float* W0_h = (const float*)d_in[6];
    const float* b0_h = (const float*)d_in[7];
    const float* W1_h = (const float*)d_in[8];
    const float* b1_h = (const float*)d_in[9];
    const float* W0_l = (const float*)d_in[10];
    const float* b0_l = (const float*)d_in[11];
    const float* W1_l = (const float*)d_in[12];
    const float* b1_l = (const float*)d_in[13];

    const int N_ = 100000, E_ = 300000;
    float* vert = (float*)d_out;                    // N*3
    float* aux  = (float*)d_out + (size_t)N_ * 3;   // N*128 fp32

    char* w = (char*)d_ws;
    auto alloc = [&](size_t bytes) {
        char* p = w;
        w += (bytes + 255) & ~(size_t)255;
        return p;
    };
    unsigned short* wb    = (unsigned short*)alloc((size_t)13 * 32768 * 2);
    unsigned short* xf    = (unsigned short*)alloc((size_t)N_ * D * 2);
    unsigned short* resid = (unsigned short*)alloc((size_t)N_ * D * 2);
    unsigned short* xa    = (unsigned short*)alloc((size_t)N_ * D * 2);
    unsigned short* xb    = (unsigned short*)alloc((size_t)N_ * D * 2);
    unsigned short* sb    = (unsigned short*)alloc((size_t)N_ * D * 2);
    int* deg    = (int*)alloc((size_t)N_ * 4);
    int* incl   = (int*)alloc((size_t)N_ * 4);
    int* rowst  = (int*)alloc((size_t)(N_ + 1) * 4);
    int* cursor = (int*)alloc((size_t)N_ * 4);
    int* bsum   = (int*)alloc(128 * 4);
    int* adj    = (int*)alloc((size_t)2 * E_ * 4);
    int* own    = (int*)alloc((size_t)2 * E_ * 4);

    // CSR build
    hipMemsetAsync(deg, 0, (size_t)N_ * 4, stream);
    k_hist<<<(E_ + 255) / 256, 256, 0, stream>>>(edges, E_, deg);
    int nb = (N_ + 1023) / 1024;   // 98
    k_scan1<<<nb, 1024, 0, stream>>>(deg, N_, incl, bsum);
    k_scan2<<<1, 128, 0, stream>>>(bsum, nb);
    k_scan3<<<(N_ + 255) / 256, 256, 0, stream>>>(incl, deg, bsum, N_, 2 * E_, rowst, cursor);
    k_fill<<<(E_ + 255) / 256, 256, 0, stream>>>(edges, E_, cursor, adj, own);

    // weight + feature conversion
    k_wprep<<<(13 * 2 * 16384 + 255) / 256, 256, 0, stream>>>(W0_1, W1_1, W0_h, W1_h, wb);
    k_cvt<<<(N_ * D / 4 + 255) / 256, 256, 0, stream>>>(features, xf, N_ * D / 4);

    int gblocks = (N_ + 127) / 128;   // 782
    int ablocks = (N_ + 3) / 4;

    // layer 1: xf -> resid (fused agg+gemm)
    k_fused<<<gblocks, 256, 0, stream>>>(xf, wb, b0_1, b1_1, rowst, adj, own, deg,
                                         resid, nullptr, nullptr, nullptr, N_, 1);

    // 12 hidden layers (fused); layer 12 also writes aux (fp32) and z = resid + x12 -> xf
    for (int h = 0; h < 12; ++h) {
        const unsigned short* in = (h == 0) ? resid : ((h & 1) ? xa : xb);
        unsigned short* outp = (h & 1) ? xb : xa;
        float* o32 = (h == 11) ? aux : nullptr;
        const unsigned short* radd = (h == 11) ? resid : nullptr;
        unsigned short* zo = (h == 11) ? xf : nullptr;
        k_fused<<<gblocks, 256, 0, stream>>>(in, wb + (size_t)(1 + h) * 32768,
                                             b0_h + h * 128, b1_h + h * 128,
                                             rowst, adj, own, deg, outp, o32, radd, zo, N_, 1);
    }

    // last layer: z (in xf); vertices = gconv(z), no relu
    k_agg<<<ablocks, 256, 0, stream>>>(xf, rowst, adj, sb, N_);
    k_last<<<ablocks, 256, 0, stream>>>(xf, sb, W0_l, b0_l, W1_l, b1_l, deg, vert, N_);
}

// Round 4
// 1259.838 us; speedup vs baseline: 5.5580x; 5.5580x over previous
//
#include <hip/hip_runtime.h>
#include <hip/hip_bf16.h>

#define D 128
#define OSTR 136   // LDS row stride (shorts) for epilogue transpose

typedef float f32x4  __attribute__((ext_vector_type(4)));
typedef __attribute__((ext_vector_type(8))) __bf16 bh8;

union UV { uint4 u; bh8 h; };

__device__ inline float bf2f(unsigned short u) {
    union { unsigned int i; float f; } x; x.i = ((unsigned int)u) << 16; return x.f;
}
__device__ inline unsigned short f2bf(float f) {
    union { float f; unsigned int i; } x; x.f = f;
    return (unsigned short)((x.i + 0x7fffu + ((x.i >> 16) & 1u)) >> 16);
}
__device__ inline void acc2(unsigned int u, float& a, float& b) {
    union { unsigned int i; float f; } lo, hi;
    lo.i = u << 16; hi.i = u & 0xffff0000u;
    a += lo.f; b += hi.f;
}
__device__ inline unsigned int addb2(unsigned int ua, unsigned int ub) {
    union { unsigned int i; float f; } la, ha, lb, hb;
    la.i = ua << 16; ha.i = ua & 0xffff0000u;
    lb.i = ub << 16; hb.i = ub & 0xffff0000u;
    return ((unsigned int)f2bf(ha.f + hb.f) << 16) | f2bf(la.f + lb.f);
}

// ---------------- CSR build ----------------
__global__ void k_hist(const int* __restrict__ edges, int E, int* __restrict__ deg) {
    int e = blockIdx.x * blockDim.x + threadIdx.x;
    if (e < E) {
        atomicAdd(&deg[edges[2 * e]], 1);
        atomicAdd(&deg[edges[2 * e + 1]], 1);
    }
}

__global__ void k_scan1(const int* __restrict__ deg, int n,
                        int* __restrict__ incl, int* __restrict__ bsum) {
    __shared__ int lds[1024];
    int t = threadIdx.x;
    int i = blockIdx.x * 1024 + t;
    int v = (i < n) ? deg[i] : 0;
    int cur = v;
    lds[t] = cur;
    __syncthreads();
    for (int off = 1; off < 1024; off <<= 1) {
        int add = (t >= off) ? lds[t - off] : 0;
        __syncthreads();
        cur += add;
        lds[t] = cur;
        __syncthreads();
    }
    if (i < n) incl[i] = cur;
    if (t == 1023) bsum[blockIdx.x] = cur;
}

__global__ void k_scan2(int* __restrict__ bsum, int nb) {
    __shared__ int lds[128];
    int t = threadIdx.x;
    int v = (t < nb) ? bsum[t] : 0;
    int cur = v;
    lds[t] = cur;
    __syncthreads();
    for (int off = 1; off < 128; off <<= 1) {
        int add = (t >= off) ? lds[t - off] : 0;
        __syncthreads();
        cur += add;
        lds[t] = cur;
        __syncthreads();
    }
    if (t < nb) bsum[t] = cur - v;  // exclusive
}

__global__ void k_scan3(const int* __restrict__ incl, const int* __restrict__ deg,
                        const int* __restrict__ bsum, int n, int twoE,
                        int* __restrict__ rowstart, int* __restrict__ cursor) {
    int i = blockIdx.x * blockDim.x + threadIdx.x;
    if (i < n) {
        int r = incl[i] - deg[i] + bsum[i >> 10];
        rowstart[i] = r;
        cursor[i] = r;
    }
    if (i == 0) rowstart[n] = twoE;
}

__global__ void k_fill(const int* __restrict__ edges, int E,
                       int* __restrict__ cursor, int* __restrict__ adj) {
    int e = blockIdx.x * blockDim.x + threadIdx.x;
    if (e < E) {
        int a = edges[2 * e], b = edges[2 * e + 1];
        adj[atomicAdd(&cursor[a], 1)] = b;
        adj[atomicAdd(&cursor[b], 1)] = a;
    }
}

// ---------------- weight prep: bf16, K-chunked layout ----------------
// wb[l][chunk=kk>>5][o][kk&31], kk = m*128+k (m=0: W0, m=1: W1)
__global__ void k_wprep(const float* __restrict__ W0_1, const float* __restrict__ W1_1,
                        const float* __restrict__ W0_h, const float* __restrict__ W1_h,
                        unsigned short* __restrict__ wb) {
    int idx = blockIdx.x * 256 + threadIdx.x;
    if (idx >= 13 * 2 * 128 * 128) return;
    int k = idx & 127;
    int o = (idx >> 7) & 127;
    int m = (idx >> 14) & 1;
    int l = idx >> 15;
    const float* src = (l == 0) ? (m ? W1_1 : W0_1)
                                : ((m ? W1_h : W0_h) + (size_t)(l - 1) * 16384);
    float v = src[o * 128 + k];
    int kk = m * 128 + k;
    wb[(size_t)l * 32768 + (kk >> 5) * 4096 + o * 32 + (kk & 31)] = f2bf(v);
}

// ---------------- fp32 -> bf16 convert ----------------
__global__ void k_cvt(const float* __restrict__ in, unsigned short* __restrict__ out, int n4) {
    int i = blockIdx.x * blockDim.x + threadIdx.x;
    if (i >= n4) return;
    f32x4 v = *(const f32x4*)&in[(size_t)i * 4];
    unsigned short u[4];
    #pragma unroll
    for (int j = 0; j < 4; ++j) u[j] = f2bf(v[j]);
    *(uint2*)&out[(size_t)i * 4] = *(uint2*)u;
}

// ---------------- neighbor aggregation (bf16 in/out, fp32 accum) ----------------
// wave per node; one vector adj load + shfl broadcast => up to 8 row-loads in flight
__global__ __launch_bounds__(256) void k_agg(
    const unsigned short* __restrict__ x, const int* __restrict__ rowstart,
    const int* __restrict__ adj, unsigned short* __restrict__ s, int n) {
    int node = blockIdx.x * 4 + (threadIdx.x >> 6);
    int lane = threadIdx.x & 63;
    if (node >= n) return;
    int r0 = rowstart[node], r1 = rowstart[node + 1];
    float a[8], b[8];
    #pragma unroll
    for (int k = 0; k < 8; ++k) { a[k] = 0.f; b[k] = 0.f; }
    for (int p = r0; p < r1; p += 8) {
        int q = p + (lane & 7);
        int idx = (q < r1) ? adj[q] : 0;
        unsigned int u[8];
        #pragma unroll
        for (int k = 0; k < 8; ++k) {
            int j = __shfl(idx, k);
            u[k] = *(const unsigned int*)&x[(size_t)j * D + lane * 2];
        }
        #pragma unroll
        for (int k = 0; k < 8; ++k)
            if (p + k < r1) acc2(u[k], a[k], b[k]);
    }
    float f0 = ((a[0] + a[1]) + (a[2] + a[3])) + ((a[4] + a[5]) + (a[6] + a[7]));
    float f1 = ((b[0] + b[1]) + (b[2] + b[3])) + ((b[4] + b[5]) + (b[6] + b[7]));
    unsigned int out = ((unsigned int)f2bf(f1) << 16) | f2bf(f0);
    *(unsigned int*)&s[(size_t)node * D + lane * 2] = out;
}

// ---------------- MFMA GEMM, barrier-free main loop ----------------
// out[i][o] = act([x_i, s_i] @ [W0T;W1T] + b0 + deg*b1)
// 256 threads = 4 waves; block tile 128 nodes x 128 outs; K=256 in 8 chunks of 32.
// A and B fragments are read DIRECTLY from global memory (x/s rows are row-major
// == fragment layout; wb is the 64KB L2-broadcast chunked weight array), so the
// main loop has no LDS traffic and no barriers — 64 independent 16B loads fully
// unrolled give the ILP that the staged version's drain barriers destroyed.
// Epilogue transposes through LDS for fully-coalesced uint4 stores; optional
// fp32 aux copy and optional fused residual add (zout = out + resid).
__global__ __launch_bounds__(256) void k_gemm(
    const unsigned short* __restrict__ x,   // [n][128] bf16
    const unsigned short* __restrict__ s,   // [n][128] bf16
    const unsigned short* __restrict__ wb,  // layer weights, chunked [8][128][32] bf16
    const float* __restrict__ b0, const float* __restrict__ b1,
    const int* __restrict__ deg,
    unsigned short* __restrict__ out,       // [n][128] bf16
    float* __restrict__ out32,              // optional fp32 copy (aux), may be null
    const unsigned short* __restrict__ resid, // optional residual input (bf16)
    unsigned short* __restrict__ zout,      // optional: zout = out + resid
    int n, int do_relu) {
    __shared__ __align__(16) unsigned short LDS[128 * OSTR];  // 34816 B (epilogue only)
    int t = threadIdx.x;
    int node0 = blockIdx.x * 128;
    int lane = t & 63;
    int wave = t >> 6;
    int wm = (wave & 1) * 64;
    int wn = (wave >> 1) * 64;
    int mlane = lane & 15;
    int quad = lane >> 4;

    f32x4 acc[4][4];
    #pragma unroll
    for (int i = 0; i < 4; ++i)
        #pragma unroll
        for (int j = 0; j < 4; ++j) acc[i][j] = (f32x4){0.f, 0.f, 0.f, 0.f};

    #pragma unroll
    for (int kc = 0; kc < 8; ++kc) {
        const unsigned short* srcA = (kc < 4) ? x : s;
        int kbase = (kc & 3) * 32;
        bh8 af[4], bf_[4];
        #pragma unroll
        for (int i = 0; i < 4; ++i) {
            int g = node0 + wm + i * 16 + mlane;
            UV v; v.u = (uint4){0u, 0u, 0u, 0u};
            if (g < n) v.u = *(const uint4*)&srcA[(size_t)g * D + kbase + quad * 8];
            af[i] = v.h;
        }
        #pragma unroll
        for (int j = 0; j < 4; ++j)
            bf_[j] = *(const bh8*)&wb[(size_t)kc * 4096 + (wn + j * 16 + mlane) * 32 + quad * 8];
        #pragma unroll
        for (int i = 0; i < 4; ++i)
            #pragma unroll
            for (int j = 0; j < 4; ++j)
                acc[i][j] = __builtin_amdgcn_mfma_f32_16x16x32_bf16(af[i], bf_[j], acc[i][j], 0, 0, 0);
    }

    // ---- epilogue: bias + deg*b1 + relu -> LDS transpose -> coalesced stores ----
    #pragma unroll
    for (int i = 0; i < 4; ++i) {
        int mrow = wm + i * 16 + quad * 4;
        #pragma unroll
        for (int j = 0; j < 4; ++j) {
            int nn = wn + j * 16 + mlane;
            float b0v = b0[nn], b1v = b1[nn];
            #pragma unroll
            for (int r = 0; r < 4; ++r) {
                int g = node0 + mrow + r;
                float dg = (g < n) ? (float)deg[g] : 0.f;
                float val = acc[i][j][r] + b0v + dg * b1v;
                if (do_relu) val = fmaxf(val, 0.f);
                LDS[(mrow + r) * OSTR + nn] = f2bf(val);
            }
        }
    }
    __syncthreads();
    // bf16 store: 8 passes, 16 lanes x 16B = one full 256B node row per 16 threads
    #pragma unroll
    for (int pass = 0; pass < 8; ++pass) {
        int row = pass * 16 + (t >> 4);
        int seg = (t & 15) * 8;
        int g = node0 + row;
        if (g < n) {
            uint4 v = *(const uint4*)&LDS[row * OSTR + seg];
            *(uint4*)&out[(size_t)g * D + seg] = v;
            if (zout) {
                uint4 rr = *(const uint4*)&resid[(size_t)g * D + seg];
                uint4 zz;
                zz.x = addb2(v.x, rr.x);
                zz.y = addb2(v.y, rr.y);
                zz.z = addb2(v.z, rr.z);
                zz.w = addb2(v.w, rr.w);
                *(uint4*)&zout[(size_t)g * D + seg] = zz;
            }
        }
    }
    if (out32) {
        #pragma unroll
        for (int pass = 0; pass < 16; ++pass) {
            int row = pass * 8 + (t >> 5);
            int seg = (t & 31) * 4;
            int g = node0 + row;
            if (g < n) {
                f32x4 v;
                #pragma unroll
                for (int j = 0; j < 4; ++j) v[j] = bf2f(LDS[row * OSTR + seg + j]);
                *(f32x4*)&out32[(size_t)g * D + seg] = v;
            }
        }
    }
}

// ---------------- last layer (D_out = 3, fp32 out, no relu) ----------------
__global__ void k_last(const unsigned short* __restrict__ z, const unsigned short* __restrict__ sz,
                       const float* __restrict__ W0, const float* __restrict__ b0,
                       const float* __restrict__ W1, const float* __restrict__ b1,
                       const int* __restrict__ deg, float* __restrict__ vert, int n) {
    int t = threadIdx.x;
    int lane = t & 63;
    int node = blockIdx.x * 4 + (t >> 6);
    if (node >= n) return;
    float z0 = bf2f(z[(size_t)node * D + lane]), z1 = bf2f(z[(size_t)node * D + 64 + lane]);
    float s0 = bf2f(sz[(size_t)node * D + lane]), s1 = bf2f(sz[(size_t)node * D + 64 + lane]);
    float dg = (float)deg[node];
    #pragma unroll
    for (int o = 0; o < 3; ++o) {
        float p = z0 * W0[o * D + lane] + z1 * W0[o * D + 64 + lane]
                + s0 * W1[o * D + lane] + s1 * W1[o * D + 64 + lane];
        for (int off = 32; off > 0; off >>= 1) p += __shfl_down(p, off);
        if (lane == 0) vert[(size_t)node * 3 + o] = p + b0[o] + dg * b1[o];
    }
}

extern "C" void kernel_launch(void* const* d_in, const int* in_sizes, int n_in,
                              void* d_out, int out_size, void* d_ws, size_t ws_size,
                              hipStream_t stream) {
    const float* features = (const float*)d_in[0];
    const int*   edges    = (const int*)d_in[1];
    const float* W0_1 = (const float*)d_in[2];
    const float* b0_1 = (const float*)d_in[3];
    const float* W1_1 = (const float*)d_in[4];
    const float* b1_1 = (const float*)d_in[5];
    const float* W0_h = (const float*)d_in[6];
    const float* b0_h = (const float*)d_in[7];
    const float* W1_h = (const float*)d_in[8];
    const float* b1_h = (const float*)d_in[9];
    const float* W0_l = (const float*)d_in[10];
    const float* b0_l = (const float*)d_in[11];
    const float* W1_l = (const float*)d_in[12];
    const float* b1_l = (const float*)d_in[13];

    const int N_ = 100000, E_ = 300000;
    float* vert = (float*)d_out;                    // N*3
    float* aux  = (float*)d_out + (size_t)N_ * 3;   // N*128 fp32

    char* w = (char*)d_ws;
    auto alloc = [&](size_t bytes) {
        char* p = w;
        w += (bytes + 255) & ~(size_t)255;
        return p;
    };
    unsigned short* wb    = (unsigned short*)alloc((size_t)13 * 32768 * 2);
    unsigned short* xf    = (unsigned short*)alloc((size_t)N_ * D * 2);
    unsigned short* resid = (unsigned short*)alloc((size_t)N_ * D * 2);
    unsigned short* xa    = (unsigned short*)alloc((size_t)N_ * D * 2);
    unsigned short* xb    = (unsigned short*)alloc((size_t)N_ * D * 2);
    unsigned short* sb    = (unsigned short*)alloc((size_t)N_ * D * 2);
    int* deg    = (int*)alloc((size_t)N_ * 4);
    int* incl   = (int*)alloc((size_t)N_ * 4);
    int* rowst  = (int*)alloc((size_t)(N_ + 1) * 4);
    int* cursor = (int*)alloc((size_t)N_ * 4);
    int* bsum   = (int*)alloc(128 * 4);
    int* adj    = (int*)alloc((size_t)2 * E_ * 4);

    // CSR build
    hipMemsetAsync(deg, 0, (size_t)N_ * 4, stream);
    k_hist<<<(E_ + 255) / 256, 256, 0, stream>>>(edges, E_, deg);
    int nb = (N_ + 1023) / 1024;   // 98
    k_scan1<<<nb, 1024, 0, stream>>>(deg, N_, incl, bsum);
    k_scan2<<<1, 128, 0, stream>>>(bsum, nb);
    k_scan3<<<(N_ + 255) / 256, 256, 0, stream>>>(incl, deg, bsum, N_, 2 * E_, rowst, cursor);
    k_fill<<<(E_ + 255) / 256, 256, 0, stream>>>(edges, E_, cursor, adj);

    // weight + feature conversion
    k_wprep<<<(13 * 2 * 16384 + 255) / 256, 256, 0, stream>>>(W0_1, W1_1, W0_h, W1_h, wb);
    k_cvt<<<(N_ * D / 4 + 255) / 256, 256, 0, stream>>>(features, xf, N_ * D / 4);

    int gblocks = (N_ + 127) / 128;   // 782
    int ablocks = (N_ + 3) / 4;

    // layer 1: xf -> resid
    k_agg<<<ablocks, 256, 0, stream>>>(xf, rowst, adj, sb, N_);
    k_gemm<<<gblocks, 256, 0, stream>>>(xf, sb, wb, b0_1, b1_1, deg, resid,
                                        nullptr, nullptr, nullptr, N_, 1);

    // 12 hidden layers; layer 12 also writes aux (fp32) and z = resid + x12 -> xf
    for (int h = 0; h < 12; ++h) {
        const unsigned short* in = (h == 0) ? resid : ((h & 1) ? xa : xb);
        unsigned short* outp = (h & 1) ? xb : xa;
        float* o32 = (h == 11) ? aux : nullptr;
        const unsigned short* radd = (h == 11) ? resid : nullptr;
        unsigned short* zo = (h == 11) ? xf : nullptr;
        k_agg<<<ablocks, 256, 0, stream>>>(in, rowst, adj, sb, N_);
        k_gemm<<<gblocks, 256, 0, stream>>>(in, sb, wb + (size_t)(1 + h) * 32768,
                                            b0_h + h * 128, b1_h + h * 128, deg,
                                            outp, o32, radd, zo, N_, 1);
    }

    // last layer: z (in xf); vertices = gconv(z), no relu
    k_agg<<<ablocks, 256, 0, stream>>>(xf, rowst, adj, sb, N_);
    k_last<<<ablocks, 256, 0, stream>>>(xf, sb, W0_l, b0_l, W1_l, b1_l, deg, vert, N_);
}